// Round 3
// baseline (230.009 us; speedup 1.0000x reference)
//
#include <hip/hip_runtime.h>
#include <hip/hip_bf16.h>

// ChannelKiller: out[b,c,t] = x[b,c,t] * (c==0 ? 1.0f : 0.5f)
// B=16, C=8, T=262144 (fp32). For float4 index i4, channel = (i4>>16)&7
// (T/4 = 65536 = 2^16, C = 8).
//
// Streaming memory-bound: 268 MB traffic, floor ~43 us @ 6.3 TB/s.
// 4 float4s per thread, loads issued up-front (MLP=4), nontemporal hints
// (read-once/write-once — no cache retention needed).
// NOTE: nontemporal builtins need a NATIVE vector type, not HIP_vector_type.

typedef float f4 __attribute__((ext_vector_type(4)));

__global__ void __launch_bounds__(256)
channel_killer_kernel(const f4* __restrict__ x, f4* __restrict__ out) {
    const int tid = blockIdx.x * 256 + threadIdx.x;
    const int stride = gridDim.x * 256;

    int idx[4];
    f4  v[4];
#pragma unroll
    for (int j = 0; j < 4; ++j) {
        idx[j] = tid + j * stride;
        v[j] = __builtin_nontemporal_load(&x[idx[j]]);   // 4 loads in flight
    }
#pragma unroll
    for (int j = 0; j < 4; ++j) {
        const float s = ((idx[j] >> 16) & 7) == 0 ? 1.0f : 0.5f;
        __builtin_nontemporal_store(v[j] * s, &out[idx[j]]);
    }
}

extern "C" void kernel_launch(void* const* d_in, const int* in_sizes, int n_in,
                              void* d_out, int out_size, void* d_ws, size_t ws_size,
                              hipStream_t stream) {
    const f4* x = (const f4*)d_in[0];
    f4* out = (f4*)d_out;
    const int n = in_sizes[0];          // 33,554,432
    const int n4 = n >> 2;              // 8,388,608 float4s

    const int block = 256;
    const int grid = n4 / (block * 4);  // 8192 — exact cover, 4 float4s/thread
    channel_killer_kernel<<<grid, block, 0, stream>>>(x, out);
}